// Round 5
// baseline (9079.365 us; speedup 1.0000x reference)
//
#include <hip/hip_runtime.h>

typedef unsigned short u16;
typedef unsigned int u32;
typedef unsigned long long u64;
typedef short v8s __attribute__((ext_vector_type(8)));
typedef float v4f __attribute__((ext_vector_type(4)));

// Dims: B=256, T=512, D=32, H=256, 4H=1024, A=128, HOR=24, NQ=3
// Encoder rewritten as a 4-role pipeline per 16-row group (16 grps x 4 roles =
// 64 working blocks of 512 thr). The two latency-critical self-recurrences
// (Whh0, Whh1) each live ENTIRELY on one CU (h in LDS, weights streamed from
// L2 via frag-packed buffers). Cross-CU traffic is only lag-tolerant streams
// (h0 ring, partial-gate ring, h1 ring) -> no handoff latency on the cadence.
// Cells computed fully in-register (i/f/g/o tiles land in the same lane).

__device__ __forceinline__ float bf2f(u16 u) { union { u32 u; float f; } c; c.u = ((u32)u) << 16; return c.f; }
__device__ __forceinline__ u16 f2bf(float f) {
  union { float f; u32 u; } c; c.f = f;
  u32 r = c.u + 0x7FFFu + ((c.u >> 16) & 1u);   // RTNE
  return (u16)(r >> 16);
}
__device__ __forceinline__ float sigf(float x) { return 1.f / (1.f + __expf(-x)); }
__device__ __forceinline__ float tanhfast(float x) {
  x = fminf(15.f, fmaxf(-15.f, x));
  float e = __expf(2.f * x);
  return (e - 1.f) / (e + 1.f);
}
__device__ __forceinline__ float ldIn(const void* p, size_t i, int isbf) {
  return isbf ? bf2f(((const u16*)p)[i]) : ((const float*)p)[i];
}
__device__ __forceinline__ v8s ld8hi(const void* p, size_t e, int isbf) {
  if (isbf) return *(const v8s*)((const u16*)p + e);
  const float* f = (const float*)p + e;
  v8s r;
#pragma unroll
  for (int j = 0; j < 8; ++j) r[j] = (short)f2bf(f[j]);
  return r;
}
__device__ __forceinline__ void ld8split(const void* p, size_t e, int isbf, v8s& hi, v8s& lo) {
  if (isbf) {
    hi = *(const v8s*)((const u16*)p + e);
    lo = v8s{0, 0, 0, 0, 0, 0, 0, 0};
  } else {
    const float* f = (const float*)p + e;
#pragma unroll
    for (int j = 0; j < 8; ++j) {
      u16 h = f2bf(f[j]);
      hi[j] = (short)h;
      lo[j] = (short)f2bf(f[j] - bf2f(h));
    }
  }
}
#define MFMA(a, b, c) __builtin_amdgcn_mfma_f32_16x16x32_bf16(a, b, c, 0, 0, 0)

__device__ __forceinline__ u64 aload64(const u64* p) {
  return __hip_atomic_load(p, __ATOMIC_RELAXED, __HIP_MEMORY_SCOPE_AGENT);
}
__device__ __forceinline__ u32 aload32(const u32* p) {
  return __hip_atomic_load(p, __ATOMIC_RELAXED, __HIP_MEMORY_SCOPE_AGENT);
}
__device__ __forceinline__ void astore32(u32* p, u32 v) {
  __hip_atomic_store(p, v, __ATOMIC_RELAXED, __HIP_MEMORY_SCOPE_AGENT);
}
__device__ __forceinline__ void astore64(u64* p, u64 v) {
  __hip_atomic_store(p, v, __ATOMIC_RELAXED, __HIP_MEMORY_SCOPE_AGENT);
}

// ---- stream-in (512 threads): ring slot [16 rows][256 units] u32 (bf16|tag<<16)
// -> LDS [row][264 u16]. Spin until all embedded tags match.
__device__ __forceinline__ void stream_in(u16* dst, const u32* src, int tid, u32 tag) {
  const u64* p = (const u64*)src;
  u64 v[4];
#pragma unroll
  for (int i = 0; i < 4; ++i) v[i] = aload64(p + i * 512 + tid);
  bool all;
  do {
    all = true;
#pragma unroll
    for (int i = 0; i < 4; ++i) {
      u64 w = v[i];
      if (!((((w >> 16) & 0xFFFFull) == tag) && ((w >> 48) == tag))) {
        all = false;
        v[i] = aload64(p + i * 512 + tid);
      }
    }
  } while (!all);
#pragma unroll
  for (int i = 0; i < 4; ++i) {
    int idx = i * 512 + tid;
    int row = idx >> 7, jp = idx & 127;
    u64 w = v[i];
    ((u32*)(dst + row * 264))[jp] =
        (u32)(w & 0xFFFF) | ((((u32)(w >> 32)) & 0xFFFF) << 16);
  }
}

// ---- Decoder tagged stage (unchanged): u64/unit = hi|lo<<16|tag<<32, [16][256] u64.
__device__ __forceinline__ void stage_dec(u16* dhi, u16* dlo, const u64* src,
                                          int tid, u32 tag) {
  u64 v[16];
#pragma unroll
  for (int i = 0; i < 16; ++i) v[i] = aload64(src + i * 256 + tid);
  bool all;
  do {
    all = true;
#pragma unroll
    for (int i = 0; i < 16; ++i) {
      if ((u32)(v[i] >> 32) != tag) { all = false; v[i] = aload64(src + i * 256 + tid); }
    }
  } while (!all);
#pragma unroll
  for (int i = 0; i < 16; ++i) {
    int idx = i * 256 + tid;
    int row = idx >> 8, col = idx & 255;
    dhi[row * 264 + col] = (u16)v[i];
    dlo[row * 264 + col] = (u16)(v[i] >> 16);
  }
}
__device__ __forceinline__ void stage_f32(u16* dhi, u16* dlo, const float* src, int tid) {
#pragma unroll
  for (int i = 0; i < 8; ++i) {
    int e = i * 512 + tid * 2;
    int row = e >> 8, jc = e & 255;
    float f0 = src[row * 256 + jc], f1 = src[row * 256 + jc + 1];
    u16 h0 = f2bf(f0), h1 = f2bf(f1);
    u16 l0 = f2bf(f0 - bf2f(h0)), l1 = f2bf(f1 - bf2f(h1));
    ((u32*)(dhi + row * 264))[jc >> 1] = (u32)h0 | ((u32)h1 << 16);
    ((u32*)(dlo + row * 264))[jc >> 1] = (u32)l0 | ((u32)l1 << 16);
  }
}

__global__ void sniff_kernel(const u16* __restrict__ w, int* __restrict__ flag) {
  __shared__ int cnt;
  if (threadIdx.x == 0) cnt = 0;
  __syncthreads();
  int ok = 0;
  for (int i = threadIdx.x; i < 1024; i += 256) {
    u16 u = w[2 * i];
    int e = (u >> 7) & 0xFF;
    ok += (u == 0 || (e >= 97 && e <= 140)) ? 1 : 0;
  }
  atomicAdd(&cnt, ok);
  __syncthreads();
  if (threadIdx.x == 0) *flag = (cnt >= 768) ? 1 : 0;
}

// ---- prep: pack all weights into MFMA-B-frag order (1KB per frag, bf16).
// W0p: 576 frags = [w8][ut2][g4][k9]  (k0 = Wih0 x-part, k1..8 = Whh0)
// Wi1p/Wh1p: 512 frags = [w8][ut2][g4][k8]
// WAp: 64 frags = [w8][k8]
__global__ __launch_bounds__(256) void prep_kernel(
    const void* __restrict__ eWih0, const void* __restrict__ eWhh0,
    const void* __restrict__ eWih1, const void* __restrict__ eWhh1,
    const void* __restrict__ aW,
    u16* __restrict__ W0p, u16* __restrict__ Wi1p, u16* __restrict__ Wh1p,
    u16* __restrict__ WAp, const int* __restrict__ flagp) {
  const int isbf = *flagp;
  int fi = blockIdx.x * 256 + threadIdx.x;      // 0..106495
  int lane = fi & 63, ln = lane & 15, lq = lane >> 4;
  if (fi < 36864) {
    int f = fi >> 6;
    int k = f % 9, q = f / 9;
    int g = q & 3, ut = (q >> 2) & 1, w = q >> 3;
    int col = g * 256 + (2 * w + ut) * 16 + ln;
    v8s v;
    if (k == 0) v = ld8hi(eWih0, (size_t)col * 32 + lq * 8, isbf);
    else        v = ld8hi(eWhh0, (size_t)col * 256 + (k - 1) * 32 + lq * 8, isbf);
    *(v8s*)(W0p + f * 512 + lane * 8) = v;
  } else if (fi < 69632) {
    int f = (fi - 36864) >> 6;
    int k = f & 7, q = f >> 3;
    int g = q & 3, ut = (q >> 2) & 1, w = q >> 3;
    int col = g * 256 + (2 * w + ut) * 16 + ln;
    *(v8s*)(Wi1p + f * 512 + lane * 8) =
        ld8hi(eWih1, (size_t)col * 256 + k * 32 + lq * 8, isbf);
  } else if (fi < 102400) {
    int f = (fi - 69632) >> 6;
    int k = f & 7, q = f >> 3;
    int g = q & 3, ut = (q >> 2) & 1, w = q >> 3;
    int col = g * 256 + (2 * w + ut) * 16 + ln;
    *(v8s*)(Wh1p + f * 512 + lane * 8) =
        ld8hi(eWhh1, (size_t)col * 256 + k * 32 + lq * 8, isbf);
  } else {
    int f = (fi - 102400) >> 6;
    int k = f & 7, w = f >> 3;
    int col = w * 16 + ln;
    v8s v;
#pragma unroll
    for (int j = 0; j < 8; ++j)
      v[j] = (short)f2bf(ldIn(aW, (size_t)(k * 32 + lq * 8 + j) * 128 + col, isbf));
    *(v8s*)(WAp + f * 512 + lane * 8) = v;
  }
}

// ---------------- Encoder: 4-role pipeline ----------------
__global__ __launch_bounds__(512, 2) void enc_kernel(
    const void* __restrict__ x,
    const void* __restrict__ eb0, const void* __restrict__ eb1,
    const void* __restrict__ aV,
    const u16* __restrict__ W0p, const u16* __restrict__ Wi1p,
    const u16* __restrict__ Wh1p, const u16* __restrict__ WAp,
    u32* __restrict__ ring0, u32* __restrict__ ring1, u64* __restrict__ ringG,
    u32* __restrict__ prog,                 // [0..15]=P1, [16..31]=P2, [32..47]=P3
    float* __restrict__ ctx, const int* __restrict__ flagp) {
  __shared__ __align__(16) u16 bufA[2][16 * 264];
  __shared__ float eRed[128];
  if (blockIdx.x % 17) return;              // spread actives across XCDs (both
  const int i = blockIdx.x / 17;            // round-robin and chunked mappings)
  const int role = i >> 4, g = i & 15;
  const int isbf = *flagp;
  const int tid = threadIdx.x;
  const int w = tid >> 6, lane = tid & 63;
  const int ln = lane & 15, lq = lane >> 4;

  for (int z = tid; z < 4224; z += 512) ((u32*)bufA)[z] = 0;   // h[-1] = 0
  __syncthreads();

  if (role == 0) {
    // ======== P0: L0 self-recurrence (Whh0 + x*Wih0 + cell0) ========
    const u16* w0b = W0p + (size_t)w * 36864;
    float bg[8];
#pragma unroll
    for (int ut = 0; ut < 2; ++ut)
#pragma unroll
      for (int gg = 0; gg < 4; ++gg)
        bg[ut * 4 + gg] = ldIn(eb0, gg * 256 + (2 * w + ut) * 16 + ln, isbf);
    float c0[8] = {0, 0, 0, 0, 0, 0, 0, 0};
    const int rowbase = g * 16;
    v8s xh, xl;
    ld8split(x, ((size_t)(rowbase + ln) * 512) * 32 + lq * 8, isbf, xh, xl);
    const u32* prog1 = prog + g;
#pragma unroll 1
    for (int t = 0; t < 512; ++t) {
      const u16* hr = bufA[t & 1];
      u16* hw = bufA[(t + 1) & 1];
      v8s a[8];
#pragma unroll
      for (int k = 0; k < 8; ++k)
        a[k] = *(const v8s*)(hr + ln * 264 + k * 32 + lq * 8);
      v4f acc[8];
#pragma unroll
      for (int n = 0; n < 8; ++n) acc[n] = v4f{0, 0, 0, 0};
#pragma unroll
      for (int k = 0; k < 9; ++k) {
        v8s av = (k == 0) ? xh : a[k - 1];
#pragma unroll
        for (int n = 0; n < 8; ++n) {
          v8s wf = *(const v8s*)(w0b + (n * 9 + k) * 512 + lane * 8);
          acc[n] = MFMA(av, wf, acc[n]);
          if (k == 0 && !isbf) acc[n] = MFMA(xl, wf, acc[n]);
        }
      }
      {
        int tn = (t + 1 < 512) ? t + 1 : 511;
        ld8split(x, ((size_t)(rowbase + ln) * 512 + tn) * 32 + lq * 8, isbf, xh, xl);
      }
      if (t >= 4) {          // ring0 slot reuse: P1 must have consumed t-4
        u32 p = aload32(prog1);
        while ((int)p < t - 3) { __builtin_amdgcn_s_sleep(8); p = aload32(prog1); }
      }
      u32* r0 = ring0 + ((size_t)(t & 3) * 16 + g) * 4096;
      const u32 tg = (u32)(t + 1) << 16;
#pragma unroll
      for (int ut = 0; ut < 2; ++ut) {
        int unit = (2 * w + ut) * 16 + ln;
#pragma unroll
        for (int r = 0; r < 4; ++r) {
          float gi = acc[ut * 4 + 0][r] + bg[ut * 4 + 0];
          float gf = acc[ut * 4 + 1][r] + bg[ut * 4 + 1];
          float gz = acc[ut * 4 + 2][r] + bg[ut * 4 + 2];
          float go = acc[ut * 4 + 3][r] + bg[ut * 4 + 3];
          float& c = c0[ut * 4 + r];
          c = sigf(gf) * c + sigf(gi) * tanhfast(gz);
          float h = sigf(go) * tanhfast(c);
          u16 hb = f2bf(h);
          hw[(lq * 4 + r) * 264 + unit] = hb;
          astore32(r0 + (lq * 4 + r) * 256 + unit, (u32)hb | tg);
        }
      }
      __syncthreads();        // drains LDS + ring stores; next-step reads safe
    }
  } else if (role == 1) {
    // ======== P1: Wih1 x h0 -> partial gates (stateless stream xform) ========
    const u16* wib = Wi1p + (size_t)w * 32768;
    const u32* prog2 = prog + 16 + g;
#pragma unroll 1
    for (int s = 0; s < 512; ++s) {
      u16* hX = bufA[s & 1];
      stream_in(hX, ring0 + ((size_t)(s & 3) * 16 + g) * 4096, tid, (u32)(s + 1));
      __syncthreads();
      if (tid == 0) astore32(prog + g, (u32)s);     // h0[s] consumed
      v8s a[8];
#pragma unroll
      for (int k = 0; k < 8; ++k)
        a[k] = *(const v8s*)(hX + ln * 264 + k * 32 + lq * 8);
      v4f acc[8];
#pragma unroll
      for (int n = 0; n < 8; ++n) acc[n] = v4f{0, 0, 0, 0};
#pragma unroll
      for (int k = 0; k < 8; ++k)
#pragma unroll
        for (int n = 0; n < 8; ++n) {
          v8s wf = *(const v8s*)(wib + (n * 8 + k) * 512 + lane * 8);
          acc[n] = MFMA(a[k], wf, acc[n]);
        }
      if (s >= 4) {           // ringG slot reuse: P2 must have consumed s-4
        u32 p = aload32(prog2);
        while ((int)p < s - 3) { __builtin_amdgcn_s_sleep(8); p = aload32(prog2); }
      }
      u64* rg = ringG + ((size_t)(s & 3) * 16 + g) * 16384;
      const u64 tgg = (u64)(u32)(s + 1) << 32;
#pragma unroll
      for (int n = 0; n < 8; ++n) {
        int col = (n & 3) * 256 + (2 * w + (n >> 2)) * 16 + ln;
#pragma unroll
        for (int r = 0; r < 4; ++r) {
          float v = acc[n][r];
          u16 hi = f2bf(v);
          u16 lo = f2bf(v - bf2f(hi));
          astore64(rg + (lq * 4 + r) * 1024 + col,
                   (u64)hi | ((u64)lo << 16) | tgg);
        }
      }
    }
  } else if (role == 2) {
    // ======== P2: L1 self-recurrence (Whh1 + pG + cell1) ========
    const u16* whb = Wh1p + (size_t)w * 32768;
    float bg[8];
#pragma unroll
    for (int ut = 0; ut < 2; ++ut)
#pragma unroll
      for (int gg = 0; gg < 4; ++gg)
        bg[ut * 4 + gg] = ldIn(eb1, gg * 256 + (2 * w + ut) * 16 + ln, isbf);
    float c1[8] = {0, 0, 0, 0, 0, 0, 0, 0};
    const u32* prog3 = prog + 32 + g;
#pragma unroll 1
    for (int t = 0; t < 512; ++t) {
      if (t > 0 && tid == 0) astore32(prog + 16 + g, (u32)(t - 1));  // pG[t-1] consumed
      const u16* hr = bufA[t & 1];
      u16* hw = bufA[(t + 1) & 1];
      v8s a[8];
#pragma unroll
      for (int k = 0; k < 8; ++k)
        a[k] = *(const v8s*)(hr + ln * 264 + k * 32 + lq * 8);
      const u64* pg = ringG + ((size_t)(t & 3) * 16 + g) * 16384;
      u64 vg[32];
#pragma unroll
      for (int n = 0; n < 8; ++n) {
        int col = (n & 3) * 256 + (2 * w + (n >> 2)) * 16 + ln;
#pragma unroll
        for (int r = 0; r < 4; ++r)
          vg[n * 4 + r] = aload64(pg + (lq * 4 + r) * 1024 + col);
      }
      v4f acc[8];
#pragma unroll
      for (int n = 0; n < 8; ++n) acc[n] = v4f{0, 0, 0, 0};
#pragma unroll
      for (int k = 0; k < 8; ++k)
#pragma unroll
        for (int n = 0; n < 8; ++n) {
          v8s wf = *(const v8s*)(whb + (n * 8 + k) * 512 + lane * 8);
          acc[n] = MFMA(a[k], wf, acc[n]);
        }
      {
        bool all;
        do {
          all = true;
#pragma unroll
          for (int n = 0; n < 8; ++n) {
            int col = (n & 3) * 256 + (2 * w + (n >> 2)) * 16 + ln;
#pragma unroll
            for (int r = 0; r < 4; ++r)
              if ((u32)(vg[n * 4 + r] >> 32) != (u32)(t + 1)) {
                all = false;
                vg[n * 4 + r] = aload64(pg + (lq * 4 + r) * 1024 + col);
              }
          }
        } while (!all);
      }
      if (t >= 4) {           // ring1 slot reuse: P3 must have consumed t-4
        u32 p = aload32(prog3);
        while ((int)p < t - 3) { __builtin_amdgcn_s_sleep(8); p = aload32(prog3); }
      }
      u32* r1 = ring1 + ((size_t)(t & 3) * 16 + g) * 4096;
      const u32 tg = (u32)(t + 1) << 16;
#pragma unroll
      for (int ut = 0; ut < 2; ++ut) {
        int unit = (2 * w + ut) * 16 + ln;
#pragma unroll
        for (int r = 0; r < 4; ++r) {
          u64 wi = vg[(ut * 4 + 0) * 4 + r], wf_ = vg[(ut * 4 + 1) * 4 + r];
          u64 wz = vg[(ut * 4 + 2) * 4 + r], wo = vg[(ut * 4 + 3) * 4 + r];
          float gi = acc[ut * 4 + 0][r] + bf2f((u16)wi) + bf2f((u16)(wi >> 16)) + bg[ut * 4 + 0];
          float gf = acc[ut * 4 + 1][r] + bf2f((u16)wf_) + bf2f((u16)(wf_ >> 16)) + bg[ut * 4 + 1];
          float gz = acc[ut * 4 + 2][r] + bf2f((u16)wz) + bf2f((u16)(wz >> 16)) + bg[ut * 4 + 2];
          float go = acc[ut * 4 + 3][r] + bf2f((u16)wo) + bf2f((u16)(wo >> 16)) + bg[ut * 4 + 3];
          float& c = c1[ut * 4 + r];
          c = sigf(gf) * c + sigf(gi) * tanhfast(gz);
          float h = sigf(go) * tanhfast(c);
          u16 hb = f2bf(h);
          hw[(lq * 4 + r) * 264 + unit] = hb;
          astore32(r1 + (lq * 4 + r) * 256 + unit, (u32)hb | tg);
        }
      }
      __syncthreads();
    }
    if (tid == 0) astore32(prog + 16 + g, 511u);
  } else {
    // ======== P3: attention + online softmax + ctx ========
    const u16* wab = WAp + (size_t)w * 4096;
    float aVl = ldIn(aV, w * 16 + ln, isbf);
    const int crow = tid >> 5, cub = (tid & 31) * 8;
    float mS = -3e38f, lS = 0.f, ctxA[8] = {0, 0, 0, 0, 0, 0, 0, 0};
#pragma unroll 1
    for (int u = 0; u < 512; ++u) {
      u16* hY = bufA[u & 1];
      stream_in(hY, ring1 + ((size_t)(u & 3) * 16 + g) * 4096, tid, (u32)(u + 1));
      __syncthreads();
      if (tid == 0) astore32(prog + 32 + g, (u32)u);   // h1[u] consumed
      v8s a[8];
#pragma unroll
      for (int k = 0; k < 8; ++k)
        a[k] = *(const v8s*)(hY + ln * 264 + k * 32 + lq * 8);
      v4f accA = {0, 0, 0, 0};
#pragma unroll
      for (int k = 0; k < 8; ++k) {
        v8s wf = *(const v8s*)(wab + k * 512 + lane * 8);
        accA = MFMA(a[k], wf, accA);
      }
      float part[4];
#pragma unroll
      for (int r = 0; r < 4; ++r) part[r] = tanhfast(accA[r]) * aVl;
#pragma unroll
      for (int m = 1; m <= 8; m <<= 1)
#pragma unroll
        for (int r = 0; r < 4; ++r) part[r] += __shfl_xor(part[r], m);
      if (ln == 0)
#pragma unroll
        for (int r = 0; r < 4; ++r) eRed[w * 16 + lq * 4 + r] = part[r];
      __syncthreads();
      float e = 0.f;
#pragma unroll
      for (int q = 0; q < 8; ++q) e += eRed[q * 16 + crow];
      float nm = fmaxf(mS, e);
      float al = __expf(mS - nm), pp = __expf(e - nm);
      lS = lS * al + pp;
      mS = nm;
      v8s hv = *(const v8s*)(hY + crow * 264 + cub);
#pragma unroll
      for (int j = 0; j < 8; ++j) ctxA[j] = ctxA[j] * al + pp * bf2f((u16)hv[j]);
    }
#pragma unroll
    for (int j = 0; j < 8; ++j)
      ctx[(size_t)(g * 16 + crow) * 256 + cub + j] = ctxA[j] / lS;
  }
}

// ---------------- Decoder: 24 steps x 2 sub-steps + projection (unchanged) -------
__global__ __launch_bounds__(256, 1) void dec_kernel(
    const void* __restrict__ x,
    const void* __restrict__ dWih0, const void* __restrict__ dWhh0, const void* __restrict__ db0,
    const void* __restrict__ dWih1, const void* __restrict__ dWhh1, const void* __restrict__ db1,
    const void* __restrict__ qW, const void* __restrict__ qb,
    const float* __restrict__ ctx,
    u64* __restrict__ H0d, u64* __restrict__ H1d, u64* __restrict__ dinpG,
    void* __restrict__ out, const int* __restrict__ flagp) {
  __shared__ u16 sAhi[16 * 264], sAlo[16 * 264], sBhi[16 * 264], sBlo[16 * 264];
  __shared__ float gb[16 * 64];
  __shared__ float dinpS[16];

  const int isbf = *flagp;
  const int tid = threadIdx.x, blk = blockIdx.x;
  const int grp = blk & 15, gs = blk >> 4;
  const int lane = tid & 63, wv = tid >> 6;
  const int ln = lane & 15, lq = lane >> 4;

  v8s W0F[8], W1F[16];
  {
    const int gw = wv * 256 + gs * 16 + ln;
    const int kq = lq * 8;
#pragma unroll
    for (int kt = 0; kt < 8; ++kt) {
      W0F[kt]     = ld8hi(dWhh0, (size_t)gw * 256 + kt * 32 + kq, isbf);
      W1F[kt]     = ld8hi(dWhh1, (size_t)gw * 256 + kt * 32 + kq, isbf);
      W1F[kt + 8] = ld8hi(dWih1, (size_t)gw * 256 + kt * 32 + kq, isbf);
    }
  }
  const int urow = tid >> 4, uu = tid & 15;
  float bg0[4], bg1[4], w0v[4];
#pragma unroll
  for (int g = 0; g < 4; ++g) {
    bg0[g] = ldIn(db0, g * 256 + gs * 16 + uu, isbf);
    bg1[g] = ldIn(db1, g * 256 + gs * 16 + uu, isbf);
    w0v[g] = ldIn(dWih0, g * 256 + gs * 16 + uu, isbf);
  }
  const int gRowU = grp * 16 + urow;
  const int gUnit = gs * 16 + uu;

  float c0 = ctx[(size_t)gRowU * 256 + gUnit];
  float c1 = c0;

#pragma unroll 1
  for (int t = 0; t < 24; ++t) {
    const int pPrev = (t + 1) & 1, pCur = t & 1;
    if (t == 0) {
      stage_f32(sAhi, sAlo, ctx + (size_t)grp * 16 * 256, tid);
      if (tid < 16)
        dinpS[tid] = ldIn(x, ((size_t)(grp * 16 + tid) * 512 + 511) * 32 + 31, isbf);
    } else {
      stage_dec(sAhi, sAlo, H0d + (size_t)pPrev * 65536 + grp * 4096, tid, (u32)(2 * t - 1));
      if (tid < 16) {
        u64 w;
        do { w = aload64(dinpG + pPrev * 256 + grp * 16 + tid); } while ((u32)(w >> 32) != (u32)(2 * t));
        dinpS[tid] = __uint_as_float((u32)w);
      }
    }
    __syncthreads();
    v4f acc = {0, 0, 0, 0};
#pragma unroll
    for (int kt = 0; kt < 8; ++kt) {
      const int off = ln * 264 + kt * 32 + lq * 8;
      acc = MFMA(*(const v8s*)(sAhi + off), W0F[kt], acc);
      acc = MFMA(*(const v8s*)(sAlo + off), W0F[kt], acc);
    }
    {
      const int bR = lq * 4;
#pragma unroll
      for (int r = 0; r < 4; ++r) gb[(bR + r) * 64 + ln * 4 + wv] = acc[r];
    }
    float di = dinpS[urow];
    __syncthreads();
    {
      const float* g0 = gb + (urow * 16 + uu) * 4;
      float gi = g0[0] + bg0[0] + di * w0v[0];
      float gf = g0[1] + bg0[1] + di * w0v[1];
      float gg = g0[2] + bg0[2] + di * w0v[2];
      float go = g0[3] + bg0[3] + di * w0v[3];
      c0 = sigf(gf) * c0 + sigf(gi) * tanhfast(gg);
      float h = sigf(go) * tanhfast(c0);
      u16 hh = f2bf(h); u16 hl = f2bf(h - bf2f(hh));
      astore64(H0d + (size_t)pCur * 65536 + gRowU * 256 + gUnit,
               (u64)hh | ((u64)hl << 16) | ((u64)(u32)(2 * t + 1) << 32));
    }
    if (t == 0) stage_f32(sBhi, sBlo, ctx + (size_t)grp * 16 * 256, tid);
    else stage_dec(sBhi, sBlo, H1d + (size_t)pPrev * 65536 + grp * 4096, tid, (u32)(2 * t));
    stage_dec(sAhi, sAlo, H0d + (size_t)pCur * 65536 + grp * 4096, tid, (u32)(2 * t + 1));
    __syncthreads();
    v4f a1 = {0, 0, 0, 0};
#pragma unroll
    for (int kt = 0; kt < 8; ++kt) {
      const int off = ln * 264 + kt * 32 + lq * 8;
      a1 = MFMA(*(const v8s*)(sBhi + off), W1F[kt], a1);
      a1 = MFMA(*(const v8s*)(sBlo + off), W1F[kt], a1);
      a1 = MFMA(*(const v8s*)(sAhi + off), W1F[kt + 8], a1);
      a1 = MFMA(*(const v8s*)(sAlo + off), W1F[kt + 8], a1);
    }
    {
      const int bR = lq * 4;
#pragma unroll
      for (int r = 0; r < 4; ++r) gb[(bR + r) * 64 + ln * 4 + wv] = a1[r];
    }
    __syncthreads();
    {
      const float* g1 = gb + (urow * 16 + uu) * 4;
      float gi = g1[0] + bg1[0], gf = g1[1] + bg1[1], gg = g1[2] + bg1[2], go = g1[3] + bg1[3];
      c1 = sigf(gf) * c1 + sigf(gi) * tanhfast(gg);
      float h = sigf(go) * tanhfast(c1);
      u16 hh = f2bf(h); u16 hl = f2bf(h - bf2f(hh));
      astore64(H1d + (size_t)pCur * 65536 + gRowU * 256 + gUnit,
               (u64)hh | ((u64)hl << 16) | ((u64)(u32)(2 * t + 2) << 32));
      if (gUnit == 0)
        astore64(dinpG + pCur * 256 + gRowU,
                 (u64)__float_as_uint(h) | ((u64)(u32)(2 * t + 2) << 32));
    }
  }
  stage_dec(sAhi, sAlo, H1d + (size_t)65536 + grp * 4096, tid, 48u);
  __syncthreads();
  if (gs < 12 && tid < 96) {
    int r = tid / 6, p = tid % 6;
    int qo = gs * 6 + p, row = grp * 16 + r;
    float s = ldIn(qb, qo, isbf);
    for (int h = 0; h < 256; ++h)
      s += (bf2f(sAhi[r * 264 + h]) + bf2f(sAlo[r * 264 + h])) * ldIn(qW, (size_t)qo * 256 + h, isbf);
    if (isbf) ((u16*)out)[row * 72 + qo] = f2bf(s);
    else      ((float*)out)[row * 72 + qo] = s;
  }
}

extern "C" void kernel_launch(void* const* d_in, const int* in_sizes, int n_in,
                              void* d_out, int out_size, void* d_ws, size_t ws_size,
                              hipStream_t stream) {
  const void* x     = d_in[0];
  const void* eWih0 = d_in[1];
  const void* eWhh0 = d_in[2];
  const void* eb0   = d_in[3];
  const void* eWih1 = d_in[4];
  const void* eWhh1 = d_in[5];
  const void* eb1   = d_in[6];
  const void* dWih0 = d_in[7];
  const void* dWhh0 = d_in[8];
  const void* db0   = d_in[9];
  const void* dWih1 = d_in[10];
  const void* dWhh1 = d_in[11];
  const void* db1   = d_in[12];
  const void* aW    = d_in[13];
  const void* aV    = d_in[14];
  const void* qW    = d_in[15];
  const void* qb    = d_in[16];

  char* wsb = (char*)d_ws;
  u64*   ringG = (u64*)(wsb + 0);              // [4][16][16][1024] u64 = 8,388,608
  u32*   ring0 = (u32*)(wsb + 8388608);        // [4][16][16][256] u32 = 1,048,576
  u32*   ring1 = (u32*)(wsb + 9437184);        // 1,048,576 -> 10,485,760
  u32*   prog  = (u32*)(wsb + 10485760);       // 256 -> 10,486,016
  int*   flag  = (int*)(wsb + 10486016);       // 256 -> 10,486,272
  float* ctx   = (float*)(wsb + 10486272);     // 262,144 -> 10,748,416
  u16*   W0p   = (u16*)(wsb + 10748416);       // 589,824 -> 11,338,240
  u16*   Wi1p  = (u16*)(wsb + 11338240);       // 524,288 -> 11,862,528
  u16*   Wh1p  = (u16*)(wsb + 11862528);       // 524,288 -> 12,386,816
  u16*   WAp   = (u16*)(wsb + 12386816);       // 65,536  -> 12,452,352
  // dec buffers OVERLAY ringG (disjoint lifetimes; memset #2 re-zeroes them
  // between enc and dec so stale ring tags can't alias dec tags):
  u64*   H0d   = (u64*)(wsb + 0);              // 1,048,576
  u64*   H1d   = (u64*)(wsb + 1048576);        // -> 2,097,152
  u64*   dinpG = (u64*)(wsb + 2097152);        // 4,096 -> 2,101,248
  // total ws: 12,452,352 bytes

  hipMemsetAsync(wsb, 0, 10486016, stream);    // rings + prog
  sniff_kernel<<<1, 256, 0, stream>>>((const u16*)eWhh0, flag);
  prep_kernel<<<416, 256, 0, stream>>>(eWih0, eWhh0, eWih1, eWhh1, aW,
                                       W0p, Wi1p, Wh1p, WAp, flag);
  enc_kernel<<<1088, 512, 0, stream>>>(x, eb0, eb1, aV, W0p, Wi1p, Wh1p, WAp,
                                       ring0, ring1, ringG, prog, ctx, flag);
  hipMemsetAsync(wsb, 0, 2101248, stream);     // zero dec buffers (overlay)
  dec_kernel<<<256, 256, 0, stream>>>(x, dWih0, dWhh0, db0, dWih1, dWhh1, db1,
                                      qW, qb, ctx, H0d, H1d, dinpG,
                                      d_out, flag);
}

// Round 6
// 2064.073 us; speedup vs baseline: 4.3988x; 4.3988x over previous
//
#include <hip/hip_runtime.h>

typedef unsigned short u16;
typedef unsigned int u32;
typedef unsigned long long u64;
typedef short v8s __attribute__((ext_vector_type(8)));
typedef float v4f __attribute__((ext_vector_type(4)));

// Dims: B=256, T=512, D=32, H=256, 4H=1024, A=128, HOR=24, NQ=3
// 256 blocks = 16 groups (16 batch rows) x 16 slices (16 units = 64 gate-cols).
// Weights register-resident as MFMA B-frags (proven R0 design). Key change vs
// R0: ONE rendezvous per step instead of two. Writer publishes the combined
// word  (h0[t]|tag) | (h1[t-1]|tag)<<32  as a single u64; reader does ONE
// tagged spin per step delivering both h0[t-1] and h1[t-2]. All 41 MFMAs in
// one phase -> 2 barriers/step (was 4). Everything else identical to R0.

__device__ __forceinline__ float bf2f(u16 u) { union { u32 u; float f; } c; c.u = ((u32)u) << 16; return c.f; }
__device__ __forceinline__ u16 f2bf(float f) {
  union { float f; u32 u; } c; c.f = f;
  u32 r = c.u + 0x7FFFu + ((c.u >> 16) & 1u);   // RTNE
  return (u16)(r >> 16);
}
__device__ __forceinline__ float sigf(float x) { return 1.f / (1.f + __expf(-x)); }
__device__ __forceinline__ float tanhfast(float x) {
  x = fminf(15.f, fmaxf(-15.f, x));
  float e = __expf(2.f * x);
  return (e - 1.f) / (e + 1.f);
}
__device__ __forceinline__ float ldIn(const void* p, size_t i, int isbf) {
  return isbf ? bf2f(((const u16*)p)[i]) : ((const float*)p)[i];
}
__device__ __forceinline__ v8s ld8hi(const void* p, size_t e, int isbf) {
  if (isbf) return *(const v8s*)((const u16*)p + e);
  const float* f = (const float*)p + e;
  v8s r;
#pragma unroll
  for (int j = 0; j < 8; ++j) r[j] = (short)f2bf(f[j]);
  return r;
}
__device__ __forceinline__ void ld8split(const void* p, size_t e, int isbf, v8s& hi, v8s& lo) {
  if (isbf) {
    hi = *(const v8s*)((const u16*)p + e);
    lo = v8s{0, 0, 0, 0, 0, 0, 0, 0};
  } else {
    const float* f = (const float*)p + e;
#pragma unroll
    for (int j = 0; j < 8; ++j) {
      u16 h = f2bf(f[j]);
      hi[j] = (short)h;
      lo[j] = (short)f2bf(f[j] - bf2f(h));
    }
  }
}
#define MFMA(a, b, c) __builtin_amdgcn_mfma_f32_16x16x32_bf16(a, b, c, 0, 0, 0)

__device__ __forceinline__ u64 aload64(const u64* p) {
  return __hip_atomic_load(p, __ATOMIC_RELAXED, __HIP_MEMORY_SCOPE_AGENT);
}
__device__ __forceinline__ void astore64(u64* p, u64 v) {
  __hip_atomic_store(p, v, __ATOMIC_RELAXED, __HIP_MEMORY_SCOPE_AGENT);
}

// ---- Decoder tagged stage (unchanged, proven): u64/unit = hi|lo<<16|tag<<32.
__device__ __forceinline__ void stage_dec(u16* dhi, u16* dlo, const u64* src,
                                          int tid, u32 tag) {
  u64 v[16];
#pragma unroll
  for (int i = 0; i < 16; ++i) v[i] = aload64(src + i * 256 + tid);
  bool all;
  do {
    all = true;
#pragma unroll
    for (int i = 0; i < 16; ++i) {
      if ((u32)(v[i] >> 32) != tag) { all = false; v[i] = aload64(src + i * 256 + tid); }
    }
  } while (!all);
#pragma unroll
  for (int i = 0; i < 16; ++i) {
    int idx = i * 256 + tid;
    int row = idx >> 8, col = idx & 255;
    dhi[row * 264 + col] = (u16)v[i];
    dlo[row * 264 + col] = (u16)(v[i] >> 16);
  }
}
__device__ __forceinline__ void stage_f32(u16* dhi, u16* dlo, const float* src, int tid) {
#pragma unroll
  for (int i = 0; i < 8; ++i) {
    int e = i * 512 + tid * 2;
    int row = e >> 8, jc = e & 255;
    float f0 = src[row * 256 + jc], f1 = src[row * 256 + jc + 1];
    u16 h0 = f2bf(f0), h1 = f2bf(f1);
    u16 l0 = f2bf(f0 - bf2f(h0)), l1 = f2bf(f1 - bf2f(h1));
    ((u32*)(dhi + row * 264))[jc >> 1] = (u32)h0 | ((u32)h1 << 16);
    ((u32*)(dlo + row * 264))[jc >> 1] = (u32)l0 | ((u32)l1 << 16);
  }
}

__global__ void sniff_kernel(const u16* __restrict__ w, int* __restrict__ flag) {
  __shared__ int cnt;
  if (threadIdx.x == 0) cnt = 0;
  __syncthreads();
  int ok = 0;
  for (int i = threadIdx.x; i < 1024; i += 256) {
    u16 u = w[2 * i];
    int e = (u >> 7) & 0xFF;
    ok += (u == 0 || (e >= 97 && e <= 140)) ? 1 : 0;
  }
  atomicAdd(&cnt, ok);
  __syncthreads();
  if (threadIdx.x == 0) *flag = (cnt >= 768) ? 1 : 0;
}

// ---------------- Encoder: combined single-rendezvous step ----------------
__global__ __launch_bounds__(256, 1) void enc_kernel(
    const void* __restrict__ x,
    const void* __restrict__ eWih0, const void* __restrict__ eWhh0, const void* __restrict__ eb0,
    const void* __restrict__ eWih1, const void* __restrict__ eWhh1, const void* __restrict__ eb1,
    const void* __restrict__ aW, const void* __restrict__ aV,
    u64* __restrict__ C,                 // [2 par][grp16][gs16][row16][u16 units] u64
    float* __restrict__ ctx, const int* __restrict__ flagp) {
  __shared__ __align__(16) u16 h0s[16 * 264], h1s[16 * 264];
  __shared__ float gb0[16 * 64], gb1[16 * 64];
  __shared__ float eP[16 * 132];

  const int isbf = *flagp;
  const int tid = threadIdx.x, blk = blockIdx.x;
  const int grp = blk & 15, gs = blk >> 4;
  const int lane = tid & 63, wv = tid >> 6;      // wave = gate index
  const int ln = lane & 15, lq = lane >> 4;

  v8s W0F[9], W1F[16], AWF[16];
  {
    const int gw = wv * 256 + gs * 16 + ln;
    const int kq = lq * 8;
    W0F[0] = ld8hi(eWih0, (size_t)gw * 32 + kq, isbf);
#pragma unroll
    for (int kt = 0; kt < 8; ++kt) {
      W0F[kt + 1] = ld8hi(eWhh0, (size_t)gw * 256 + kt * 32 + kq, isbf);
      W1F[kt]     = ld8hi(eWhh1, (size_t)gw * 256 + kt * 32 + kq, isbf);
      W1F[kt + 8] = ld8hi(eWih1, (size_t)gw * 256 + kt * 32 + kq, isbf);
    }
#pragma unroll
    for (int kt = 0; kt < 8; ++kt)
#pragma unroll
      for (int j2 = 0; j2 < 2; ++j2) {
        v8s f;
        int ac = (2 * wv + j2) * 16 + ln;
#pragma unroll
        for (int j = 0; j < 8; ++j)
          f[j] = (short)f2bf(ldIn(aW, (size_t)(kt * 32 + kq + j) * 128 + ac, isbf));
        AWF[kt * 2 + j2] = f;
      }
  }

  const int urow = tid >> 4, uu = tid & 15;
  float bg0[4], bg1[4], aVr[8];
#pragma unroll
  for (int g = 0; g < 4; ++g) {
    bg0[g] = ldIn(eb0, g * 256 + gs * 16 + uu, isbf);
    bg1[g] = ldIn(eb1, g * 256 + gs * 16 + uu, isbf);
  }
#pragma unroll
  for (int j = 0; j < 8; ++j) aVr[j] = ldIn(aV, (size_t)(uu + 16 * j), isbf);

  const int gRowU = grp * 16 + urow;
  const int gUnit = gs * 16 + uu;
  const int aRow = grp * 16 + ln;
  const u32 stOff = (u32)(grp * 4096 + gs * 256 + urow * 16 + uu);   // u64 index

  float c0 = 0.f, c1 = 0.f;
  float mS = -3e38f, lS = 0.f, ctxA = 0.f;

  v8s xh_c, xl_c;
  ld8split(x, ((size_t)aRow * 512) * 32 + lq * 8, isbf, xh_c, xl_c);
  v8s a0r[8];

  // step t: combined spin (tag t) -> h0[t-1], h1[t-2]; compute h0[t], h1[t-1];
  // publish combined (tag t+1); attn consumes h1[t-2].
#pragma unroll 1
  for (int t = 0; t < 514; ++t) {
    const int rPar = (t + 1) & 1, wPar = t & 1;
    const u32 tag = (u32)(u16)t;
    // ---- S1: ONE tagged spin on the combined buffer
    {
      const u64* src = C + (size_t)rPar * 65536 + grp * 4096;
      u64 v[16];
#pragma unroll
      for (int i = 0; i < 16; ++i) v[i] = aload64(src + i * 256 + tid);
      bool all;
      do {
        all = true;
#pragma unroll
        for (int i = 0; i < 16; ++i) {
          u64 w = v[i];
          if (!((((w >> 16) & 0xFFFFull) == tag) && ((w >> 48) == tag))) {
            all = false;
            v[i] = aload64(src + i * 256 + tid);
          }
        }
      } while (!all);
      // idx = i*256+tid -> gs2=i, row=tid>>4, unit col = i*16 + (tid&15)
#pragma unroll
      for (int i = 0; i < 16; ++i) {
        u64 w = v[i];
        h0s[urow * 264 + i * 16 + uu] = (u16)w;
        h1s[urow * 264 + i * 16 + uu] = (u16)(w >> 32);
      }
    }
    __syncthreads();                                   // b1: h0s/h1s ready

    // ---- P1: ALL MFMAs in one phase
#pragma unroll
    for (int kt = 0; kt < 8; ++kt)
      a0r[kt] = *(const v8s*)(h0s + ln * 264 + kt * 32 + lq * 8);
    if (t < 512) {
      v4f acc0 = {0, 0, 0, 0};
      acc0 = MFMA(xh_c, W0F[0], acc0);
      if (!isbf) acc0 = MFMA(xl_c, W0F[0], acc0);
#pragma unroll
      for (int kt = 0; kt < 8; ++kt) acc0 = MFMA(a0r[kt], W0F[kt + 1], acc0);
#pragma unroll
      for (int r = 0; r < 4; ++r) gb0[(lq * 4 + r) * 64 + ln * 4 + wv] = acc0[r];
    }
    {
      v4f acc1 = {0, 0, 0, 0}, accA0 = {0, 0, 0, 0}, accA1 = {0, 0, 0, 0};
#pragma unroll
      for (int kt = 0; kt < 8; ++kt) {
        v8s a1 = *(const v8s*)(h1s + ln * 264 + kt * 32 + lq * 8);
        acc1 = MFMA(a0r[kt], W1F[kt + 8], acc1);
        acc1 = MFMA(a1, W1F[kt], acc1);
        accA0 = MFMA(a1, AWF[kt * 2], accA0);
        accA1 = MFMA(a1, AWF[kt * 2 + 1], accA1);
      }
#pragma unroll
      for (int r = 0; r < 4; ++r) {
        gb1[(lq * 4 + r) * 64 + ln * 4 + wv] = acc1[r];
        eP[(lq * 4 + r) * 132 + (2 * wv) * 16 + ln] = accA0[r];
        eP[(lq * 4 + r) * 132 + (2 * wv + 1) * 16 + ln] = accA1[r];
      }
    }
    // x prefetch for t+1 (off the critical path)
    v8s xh_n, xl_n;
    {
      int tn = (t + 1 < 512) ? t + 1 : 511;
      ld8split(x, ((size_t)aRow * 512 + tn) * 32 + lq * 8, isbf, xh_n, xl_n);
    }
    float h1v = bf2f(h1s[urow * 264 + gUnit]);   // hoisted: h0s/h1s not read after b2
    __syncthreads();                                   // b2: gb0/gb1/eP ready

    // ---- P2: both cells in-thread, ONE combined u64 publish; attention tail
    const u32 tagS = (u32)(u16)(t + 1) << 16;
    if (t <= 512) {
      u32 w0 = tagS, w1 = tagS;                        // defaults: value 0
      if (t < 512) {
        const float* g0 = gb0 + (urow * 16 + uu) * 4;
        float gi = g0[0] + bg0[0], gf = g0[1] + bg0[1], gg = g0[2] + bg0[2], go = g0[3] + bg0[3];
        c0 = sigf(gf) * c0 + sigf(gi) * tanhfast(gg);
        float h = sigf(go) * tanhfast(c0);
        w0 |= (u32)f2bf(h);
      }
      if (t >= 1) {
        const float* g1 = gb1 + (urow * 16 + uu) * 4;
        float gi = g1[0] + bg1[0], gf = g1[1] + bg1[1], gg = g1[2] + bg1[2], go = g1[3] + bg1[3];
        c1 = sigf(gf) * c1 + sigf(gi) * tanhfast(gg);
        float h = sigf(go) * tanhfast(c1);
        w1 |= (u32)f2bf(h);
      }
      astore64(C + (size_t)wPar * 65536 + stOff, (u64)w0 | ((u64)w1 << 32));
    }
    if (t >= 2) {
      float e = 0.f;
#pragma unroll
      for (int j = 0; j < 8; ++j)
        e += tanhfast(eP[urow * 132 + uu + 16 * j]) * aVr[j];
      e += __shfl_xor(e, 1);
      e += __shfl_xor(e, 2);
      e += __shfl_xor(e, 4);
      e += __shfl_xor(e, 8);
      float nm = fmaxf(mS, e);
      float al = __expf(mS - nm), p = __expf(e - nm);
      lS = lS * al + p;
      ctxA = ctxA * al + p * h1v;
      mS = nm;
    }
    xh_c = xh_n; xl_c = xl_n;
  }
  ctx[(size_t)gRowU * 256 + gUnit] = ctxA / lS;
}

// ---------------- Decoder: 24 steps x 2 sub-steps + projection (unchanged) -------
__global__ __launch_bounds__(256, 1) void dec_kernel(
    const void* __restrict__ x,
    const void* __restrict__ dWih0, const void* __restrict__ dWhh0, const void* __restrict__ db0,
    const void* __restrict__ dWih1, const void* __restrict__ dWhh1, const void* __restrict__ db1,
    const void* __restrict__ qW, const void* __restrict__ qb,
    const float* __restrict__ ctx,
    u64* __restrict__ H0d, u64* __restrict__ H1d, u64* __restrict__ dinpG,
    void* __restrict__ out, const int* __restrict__ flagp) {
  __shared__ u16 sAhi[16 * 264], sAlo[16 * 264], sBhi[16 * 264], sBlo[16 * 264];
  __shared__ float gb[16 * 64];
  __shared__ float dinpS[16];

  const int isbf = *flagp;
  const int tid = threadIdx.x, blk = blockIdx.x;
  const int grp = blk & 15, gs = blk >> 4;
  const int lane = tid & 63, wv = tid >> 6;
  const int ln = lane & 15, lq = lane >> 4;

  v8s W0F[8], W1F[16];
  {
    const int gw = wv * 256 + gs * 16 + ln;
    const int kq = lq * 8;
#pragma unroll
    for (int kt = 0; kt < 8; ++kt) {
      W0F[kt]     = ld8hi(dWhh0, (size_t)gw * 256 + kt * 32 + kq, isbf);
      W1F[kt]     = ld8hi(dWhh1, (size_t)gw * 256 + kt * 32 + kq, isbf);
      W1F[kt + 8] = ld8hi(dWih1, (size_t)gw * 256 + kt * 32 + kq, isbf);
    }
  }
  const int urow = tid >> 4, uu = tid & 15;
  float bg0[4], bg1[4], w0v[4];
#pragma unroll
  for (int g = 0; g < 4; ++g) {
    bg0[g] = ldIn(db0, g * 256 + gs * 16 + uu, isbf);
    bg1[g] = ldIn(db1, g * 256 + gs * 16 + uu, isbf);
    w0v[g] = ldIn(dWih0, g * 256 + gs * 16 + uu, isbf);
  }
  const int gRowU = grp * 16 + urow;
  const int gUnit = gs * 16 + uu;

  float c0 = ctx[(size_t)gRowU * 256 + gUnit];
  float c1 = c0;

#pragma unroll 1
  for (int t = 0; t < 24; ++t) {
    const int pPrev = (t + 1) & 1, pCur = t & 1;
    if (t == 0) {
      stage_f32(sAhi, sAlo, ctx + (size_t)grp * 16 * 256, tid);
      if (tid < 16)
        dinpS[tid] = ldIn(x, ((size_t)(grp * 16 + tid) * 512 + 511) * 32 + 31, isbf);
    } else {
      stage_dec(sAhi, sAlo, H0d + (size_t)pPrev * 65536 + grp * 4096, tid, (u32)(2 * t - 1));
      if (tid < 16) {
        u64 w;
        do { w = aload64(dinpG + pPrev * 256 + grp * 16 + tid); } while ((u32)(w >> 32) != (u32)(2 * t));
        dinpS[tid] = __uint_as_float((u32)w);
      }
    }
    __syncthreads();
    v4f acc = {0, 0, 0, 0};
#pragma unroll
    for (int kt = 0; kt < 8; ++kt) {
      const int off = ln * 264 + kt * 32 + lq * 8;
      acc = MFMA(*(const v8s*)(sAhi + off), W0F[kt], acc);
      acc = MFMA(*(const v8s*)(sAlo + off), W0F[kt], acc);
    }
    {
      const int bR = lq * 4;
#pragma unroll
      for (int r = 0; r < 4; ++r) gb[(bR + r) * 64 + ln * 4 + wv] = acc[r];
    }
    float di = dinpS[urow];
    __syncthreads();
    {
      const float* g0 = gb + (urow * 16 + uu) * 4;
      float gi = g0[0] + bg0[0] + di * w0v[0];
      float gf = g0[1] + bg0[1] + di * w0v[1];
      float gg = g0[2] + bg0[2] + di * w0v[2];
      float go = g0[3] + bg0[3] + di * w0v[3];
      c0 = sigf(gf) * c0 + sigf(gi) * tanhfast(gg);
      float h = sigf(go) * tanhfast(c0);
      u16 hh = f2bf(h); u16 hl = f2bf(h - bf2f(hh));
      astore64(H0d + (size_t)pCur * 65536 + gRowU * 256 + gUnit,
               (u64)hh | ((u64)hl << 16) | ((u64)(u32)(2 * t + 1) << 32));
    }
    if (t == 0) stage_f32(sBhi, sBlo, ctx + (size_t)grp * 16 * 256, tid);
    else stage_dec(sBhi, sBlo, H1d + (size_t)pPrev * 65536 + grp * 4096, tid, (u32)(2 * t));
    stage_dec(sAhi, sAlo, H0d + (size_t)pCur * 65536 + grp * 4096, tid, (u32)(2 * t + 1));
    __syncthreads();
    v4f a1 = {0, 0, 0, 0};
#pragma unroll
    for (int kt = 0; kt < 8; ++kt) {
      const int off = ln * 264 + kt * 32 + lq * 8;
      a1 = MFMA(*(const v8s*)(sBhi + off), W1F[kt], a1);
      a1 = MFMA(*(const v8s*)(sBlo + off), W1F[kt], a1);
      a1 = MFMA(*(const v8s*)(sAhi + off), W1F[kt + 8], a1);
      a1 = MFMA(*(const v8s*)(sAlo + off), W1F[kt + 8], a1);
    }
    {
      const int bR = lq * 4;
#pragma unroll
      for (int r = 0; r < 4; ++r) gb[(bR + r) * 64 + ln * 4 + wv] = a1[r];
    }
    __syncthreads();
    {
      const float* g1 = gb + (urow * 16 + uu) * 4;
      float gi = g1[0] + bg1[0], gf = g1[1] + bg1[1], gg = g1[2] + bg1[2], go = g1[3] + bg1[3];
      c1 = sigf(gf) * c1 + sigf(gi) * tanhfast(gg);
      float h = sigf(go) * tanhfast(c1);
      u16 hh = f2bf(h); u16 hl = f2bf(h - bf2f(hh));
      astore64(H1d + (size_t)pCur * 65536 + gRowU * 256 + gUnit,
               (u64)hh | ((u64)hl << 16) | ((u64)(u32)(2 * t + 2) << 32));
      if (gUnit == 0)
        astore64(dinpG + pCur * 256 + gRowU,
                 (u64)__float_as_uint(h) | ((u64)(u32)(2 * t + 2) << 32));
    }
  }
  stage_dec(sAhi, sAlo, H1d + (size_t)65536 + grp * 4096, tid, 48u);
  __syncthreads();
  if (gs < 12 && tid < 96) {
    int r = tid / 6, p = tid % 6;
    int qo = gs * 6 + p, row = grp * 16 + r;
    float s = ldIn(qb, qo, isbf);
    for (int h = 0; h < 256; ++h)
      s += (bf2f(sAhi[r * 264 + h]) + bf2f(sAlo[r * 264 + h])) * ldIn(qW, (size_t)qo * 256 + h, isbf);
    if (isbf) ((u16*)out)[row * 72 + qo] = f2bf(s);
    else      ((float*)out)[row * 72 + qo] = s;
  }
}

extern "C" void kernel_launch(void* const* d_in, const int* in_sizes, int n_in,
                              void* d_out, int out_size, void* d_ws, size_t ws_size,
                              hipStream_t stream) {
  const void* x     = d_in[0];
  const void* eWih0 = d_in[1];
  const void* eWhh0 = d_in[2];
  const void* eb0   = d_in[3];
  const void* eWih1 = d_in[4];
  const void* eWhh1 = d_in[5];
  const void* eb1   = d_in[6];
  const void* dWih0 = d_in[7];
  const void* dWhh0 = d_in[8];
  const void* db0   = d_in[9];
  const void* dWih1 = d_in[10];
  const void* dWhh1 = d_in[11];
  const void* db1   = d_in[12];
  const void* aW    = d_in[13];
  const void* aV    = d_in[14];
  const void* qW    = d_in[15];
  const void* qb    = d_in[16];

  char* wsb = (char*)d_ws;
  u64*   C     = (u64*)(wsb + 0);              // [2][16][16][16][16] u64 = 1,048,576
  u64*   H0d   = (u64*)(wsb + 1048576);        // [2][256][256] u64 = 1,048,576
  u64*   H1d   = (u64*)(wsb + 2097152);        // -> 3,145,728
  u64*   dinpG = (u64*)(wsb + 3145728);        // [2][256] u64 = 4,096 -> 3,149,824
  int*   flag  = (int*)(wsb + 3149824);        // 256 -> 3,150,080
  float* ctx   = (float*)(wsb + 3150080);      // 262,144 -> 3,412,224
  // total ws: 3,412,224 bytes. No buffer overlays; every tagged buffer is
  // zeroed each launch (tag 0 == expected at t=0; stale tags impossible).

  hipMemsetAsync(wsb, 0, 3149824, stream);

  sniff_kernel<<<1, 256, 0, stream>>>((const u16*)eWhh0, flag);
  enc_kernel<<<256, 256, 0, stream>>>(x, eWih0, eWhh0, eb0, eWih1, eWhh1, eb1,
                                      aW, aV, C, ctx, flag);
  dec_kernel<<<256, 256, 0, stream>>>(x, dWih0, dWhh0, db0, dWih1, dWhh1, db1,
                                      qW, qb, ctx, H0d, H1d, dinpG,
                                      d_out, flag);
}